// Round 11
// baseline (321.847 us; speedup 1.0000x reference)
//
#include <hip/hip_runtime.h>
#include <hip/hip_bf16.h>

#define HH 448
#define WW 608
#define CC 128
#define HWP (HH*WW)
#define G 8   // experts per K2 block (4 waves x 2 rounds)

typedef __attribute__((ext_vector_type(8))) short bf16x8;
typedef __attribute__((ext_vector_type(4))) float f32x4;

__device__ __forceinline__ ushort f2b(float f) {
    __hip_bfloat16 b = __float2bfloat16(f);
    return *reinterpret_cast<ushort*>(&b);
}
__device__ __forceinline__ float lrelu(float a) { return a > 0.f ? a : 0.01f * a; }

// Wcs swizzle: [m][k], k<128. group = (k>>3) ^ (m&15) -> frag reads 2-way (free)
__device__ __forceinline__ int swzA(int m, int k) {
    return m * 128 + ((((k >> 3) ^ (m & 15)) & 15) << 3) + (k & 7);
}
// Xs swizzle: [n][k], k<64. group = (k>>3) ^ (n&7) ^ ((n>>3)&7)
__device__ __forceinline__ int swzB(int n, int k) {
    return n * 64 + ((((k >> 3) ^ (n & 7) ^ ((n >> 3) & 7)) & 7) << 3) + (k & 7);
}

// ---------------- Kernel 1: MFMA classifier + in-register softmax/loss ----------------
// (LDS-staged Wc; no-max softmax — absmax-validated in rounds 9/10)
__global__ __launch_bounds__(512, 4) void k1_mfma(
    const float* __restrict__ x, const float* __restrict__ x_gt,
    const float* __restrict__ Wc, const float* __restrict__ bc,
    float* __restrict__ loss_out, int* __restrict__ labels,
    ushort* __restrict__ xT, int use_xT)
{
    __shared__ ushort Wcs[128 * 128];
    __shared__ ushort Xs[128 * 64];
    __shared__ float bcs[128];

    const int h  = blockIdx.y;
    const int w0 = blockIdx.x * 128;
    const int t  = threadIdx.x;
    const int wv = t >> 6, l = t & 63;
    const int q  = l >> 4, lm = l & 15;
    const int nvalid = (WW - w0 < 128) ? (WW - w0) : 128;

    const float* Wch = Wc + (size_t)h * (CC * 128);
    #pragma unroll
    for (int it = 0; it < 8; ++it) {
        int f4 = t + (it << 9);
        float4 v = reinterpret_cast<const float4*>(Wch)[f4];
        int e = f4 << 2; int m = e >> 7, kk = e & 127;
        ushort4 u = make_ushort4(f2b(v.x), f2b(v.y), f2b(v.z), f2b(v.w));
        *reinterpret_cast<ushort4*>(&Wcs[swzA(m, kk)]) = u;
    }
    if (t < 128) bcs[t] = bc[h * CC + t];

    f32x4 acc[8];
    #pragma unroll
    for (int mt = 0; mt < 8; ++mt) acc[mt] = (f32x4){0.f, 0.f, 0.f, 0.f};

    for (int kh = 0; kh < 2; ++kh) {
        if (kh) __syncthreads();
        #pragma unroll
        for (int it = 0; it < 2; ++it) {
            int p = t + (it << 9);
            int i2 = p >> 5;
            int w = (p & 31) << 2;
            float4 v0, v1;
            if (w0 + w < WW) {
                const float* xb = x + ((size_t)(kh * 64 + i2 * 2)) * HWP + (size_t)h * WW + w0 + w;
                v0 = *reinterpret_cast<const float4*>(xb);
                v1 = *reinterpret_cast<const float4*>(xb + HWP);
            } else { v0 = make_float4(0, 0, 0, 0); v1 = v0; }
            int il = i2 << 1;
            *reinterpret_cast<ushort2*>(&Xs[swzB(w + 0, il)]) = make_ushort2(f2b(v0.x), f2b(v1.x));
            *reinterpret_cast<ushort2*>(&Xs[swzB(w + 1, il)]) = make_ushort2(f2b(v0.y), f2b(v1.y));
            *reinterpret_cast<ushort2*>(&Xs[swzB(w + 2, il)]) = make_ushort2(f2b(v0.z), f2b(v1.z));
            *reinterpret_cast<ushort2*>(&Xs[swzB(w + 3, il)]) = make_ushort2(f2b(v0.w), f2b(v1.w));
        }
        __syncthreads();

        #pragma unroll
        for (int kk = 0; kk < 2; ++kk) {
            const int kb = (kk << 5) + (q << 3);
            const int kg = (kh << 6) + kb;
            bf16x8 bfrag = *reinterpret_cast<const bf16x8*>(&Xs[swzB((wv << 4) + lm, kb)]);
            #pragma unroll
            for (int mt = 0; mt < 8; ++mt) {
                bf16x8 afrag = *reinterpret_cast<const bf16x8*>(&Wcs[swzA((mt << 4) + lm, kg)]);
                acc[mt] = __builtin_amdgcn_mfma_f32_16x16x32_bf16(afrag, bfrag, acc[mt], 0, 0, 0);
            }
        }

        if (use_xT) {
            #pragma unroll
            for (int it = 0; it < 2; ++it) {
                int g = t + (it << 9);
                int n = g >> 3, i8 = g & 7;
                if (n < nvalid) {
                    bf16x8 v = *reinterpret_cast<const bf16x8*>(&Xs[swzB(n, i8 << 3)]);
                    *reinterpret_cast<bf16x8*>(xT + ((size_t)(h * WW + w0 + n)) * 128 + (kh << 6) + (i8 << 3)) = v;
                }
            }
        }
    }

    const int cn = (wv << 4) + lm;
    const int w  = w0 + cn;
    float s1 = 0.f;
    #pragma unroll
    for (int mt = 0; mt < 8; ++mt)
        #pragma unroll
        for (int r = 0; r < 4; ++r) {
            float z = acc[mt][r] + bcs[(mt << 4) + (q << 2) + r];
            z = z > 0.f ? z : 0.01f * z;
            float ev = __expf(z);
            acc[mt][r] = ev;
            s1 += ev;
        }
    s1 += __shfl_xor(s1, 16);
    s1 += __shfl_xor(s1, 32);
    const float inv = 1.f / s1;
    float s2 = 0.f;
    #pragma unroll
    for (int mt = 0; mt < 8; ++mt)
        #pragma unroll
        for (int r = 0; r < 4; ++r) s2 += __expf(acc[mt][r] * inv);
    s2 += __shfl_xor(s2, 16);
    s2 += __shfl_xor(s2, 32);

    int lab = 0;
    if (w < WW) {
        float g = x_gt[(size_t)h * WW + w];
        lab = (int)(g * 128.f);
        lab = lab < 0 ? 0 : (lab > 127 ? 127 : lab);
    }
    float pl = 0.f;
    #pragma unroll
    for (int mt = 0; mt < 8; ++mt)
        #pragma unroll
        for (int r = 0; r < 4; ++r)
            if (((mt << 4) + (q << 2) + r) == lab) pl = acc[mt][r] * inv;
    pl += __shfl_xor(pl, 16);
    pl += __shfl_xor(pl, 32);

    if (q == 0 && w < WW) {
        loss_out[(size_t)h * WW + w] = __logf(s2) - pl;
        labels[h * WW + w] = lab;
    }
}

// ---------------- Kernel 2 (v6): serial R8 structure, chunked convert, 16 waves/CU ----------------
// grid (16, 448), block 256 (4 waves). Wave wv -> experts c0+wv, c0+wv+4, serial.
// __launch_bounds__(256,4): VGPR cap 128 -> 16 waves/CU (2x R8 TLP for the 80-load chain).
template<int USE_XT>
__global__ __launch_bounds__(256, 4) void k2_mfma(
    const float* __restrict__ x, const ushort* __restrict__ xT,
    const int* __restrict__ labels,
    const float* __restrict__ W1, const float* __restrict__ b1,
    const float* __restrict__ W2, const float* __restrict__ b2,
    const float* __restrict__ Wrc, const float* __restrict__ brc,
    float* __restrict__ out)
{
    __shared__ ushort wlist[WW];
    __shared__ int cnt8[G], off8[G], cur8[G];
    __shared__ ushort __align__(16) hA[4][16][40];   // [wave][p][o] bf16, 80B rows
    __shared__ float h2s[4][16][33];
    __shared__ float wrcs[4][64];

    const int cg = blockIdx.x, h = blockIdx.y;
    const int c0 = cg * G;
    const size_t E0 = (size_t)h * CC + c0;
    const int t = threadIdx.x;
    const int wv = t >> 6, l = t & 63;
    const int lo = l & 15, g = l >> 4;

    if (t < G) { cnt8[t] = 0; cur8[t] = 0; }
    __syncthreads();

    const int* lrow = labels + h * WW;
    int myl[3];
    #pragma unroll
    for (int p = 0; p < 3; ++p) {
        int w = t + p * 256;
        myl[p] = (w < WW) ? (lrow[w] - c0) : -1;
        if (myl[p] >= 0 && myl[p] < G) atomicAdd(&cnt8[myl[p]], 1);
    }
    __syncthreads();
    if (t == 0) { int s = 0; for (int e2 = 0; e2 < G; ++e2) { off8[e2] = s; s += cnt8[e2]; } }
    __syncthreads();
    #pragma unroll
    for (int p = 0; p < 3; ++p) {
        int li = myl[p];
        if (li >= 0 && li < G) {
            int pos = off8[li] + atomicAdd(&cur8[li], 1);
            wlist[pos] = (ushort)(t + p * 256);
        }
    }
    __syncthreads();

    for (int ei = 0; ei < 2; ++ei) {
        const int li = wv + ei * 4;
        const int e_n = cnt8[li], e_off = off8[li];
        if (e_n == 0) continue;
        const size_t eg = E0 + li;
        const float* W1e = W1 + eg * 4096;
        const float* W2e = W2 + eg * 1024;

        // -- chunked load+convert: 16 fp32 staging regs per k-step (not 80 monolithic) --
        bf16x8 w1b[4][2];
        #pragma unroll
        for (int ks = 0; ks < 4; ++ks) {
            float c[2][8];
            #pragma unroll
            for (int tt = 0; tt < 2; ++tt)
                #pragma unroll
                for (int j = 0; j < 8; ++j)
                    c[tt][j] = W1e[(ks * 32 + g * 8 + j) * 32 + tt * 16 + lo];
            #pragma unroll
            for (int tt = 0; tt < 2; ++tt) {
                bf16x8 r;
                #pragma unroll
                for (int j = 0; j < 8; ++j) r[j] = (short)f2b(c[tt][j]);
                w1b[ks][tt] = r;
            }
        }
        bf16x8 w2b[2];
        {
            float c[2][8];
            #pragma unroll
            for (int tt = 0; tt < 2; ++tt)
                #pragma unroll
                for (int j = 0; j < 8; ++j)
                    c[tt][j] = W2e[(g * 8 + j) * 32 + tt * 16 + lo];
            #pragma unroll
            for (int tt = 0; tt < 2; ++tt) {
                bf16x8 r;
                #pragma unroll
                for (int j = 0; j < 8; ++j) r[j] = (short)f2b(c[tt][j]);
                w2b[tt] = r;
            }
        }
        const float b1v0 = b1[eg * 32 + lo],      b1v1 = b1[eg * 32 + 16 + lo];
        const float b2v0 = b2[eg * 32 + lo],      b2v1 = b2[eg * 32 + 16 + lo];
        const float brcv = brc[eg * 2 + (g & 1)];
        wrcs[wv][l] = Wrc[eg * 64 + l];

        for (int pb = 0; pb < e_n; pb += 16) {
            int p_idx = pb + lo;
            int pc = (p_idx < e_n) ? p_idx : (e_n - 1);
            const int wpix = wlist[e_off + pc];

            bf16x8 af[4];
            if (USE_XT) {
                const ushort* xrow = xT + (((size_t)(h * WW + wpix)) << 7);
                #pragma unroll
                for (int ks = 0; ks < 4; ++ks)
                    af[ks] = *reinterpret_cast<const bf16x8*>(xrow + ks * 32 + g * 8);
            } else {
                #pragma unroll
                for (int ks = 0; ks < 4; ++ks) {
                    bf16x8 r;
                    #pragma unroll
                    for (int j = 0; j < 8; ++j) {
                        float f = x[(size_t)(ks * 32 + g * 8 + j) * HWP + (size_t)h * WW + wpix];
                        r[j] = (short)f2b(f);
                    }
                    af[ks] = r;
                }
            }

            f32x4 a1t0 = {b1v0, b1v0, b1v0, b1v0};
            f32x4 a1t1 = {b1v1, b1v1, b1v1, b1v1};
            #pragma unroll
            for (int ks = 0; ks < 4; ++ks) {
                a1t0 = __builtin_amdgcn_mfma_f32_16x16x32_bf16(af[ks], w1b[ks][0], a1t0, 0, 0, 0);
                a1t1 = __builtin_amdgcn_mfma_f32_16x16x32_bf16(af[ks], w1b[ks][1], a1t1, 0, 0, 0);
            }
            #pragma unroll
            for (int r = 0; r < 4; ++r) {
                hA[wv][g * 4 + r][lo]      = f2b(lrelu(a1t0[r]));
                hA[wv][g * 4 + r][16 + lo] = f2b(lrelu(a1t1[r]));
            }
            bf16x8 a2 = *reinterpret_cast<const bf16x8*>(&hA[wv][lo][g * 8]);
            f32x4 a2t0 = {b2v0, b2v0, b2v0, b2v0};
            f32x4 a2t1 = {b2v1, b2v1, b2v1, b2v1};
            a2t0 = __builtin_amdgcn_mfma_f32_16x16x32_bf16(a2, w2b[0], a2t0, 0, 0, 0);
            a2t1 = __builtin_amdgcn_mfma_f32_16x16x32_bf16(a2, w2b[1], a2t1, 0, 0, 0);
            #pragma unroll
            for (int r = 0; r < 4; ++r) {
                h2s[wv][g * 4 + r][lo]      = lrelu(a2t0[r]);
                h2s[wv][g * 4 + r][16 + lo] = lrelu(a2t1[r]);
            }
            if (l < 32) {
                float a = brcv;
                #pragma unroll
                for (int i = 0; i < 32; ++i)
                    a = fmaf(h2s[wv][lo][i], wrcs[wv][i * 2 + g], a);
                a = lrelu(a);
                int p2 = pb + lo;
                if (p2 < e_n) {
                    int pix = h * WW + wlist[e_off + p2];
                    if (g == 1) out[HWP + pix] = a;
                    else        out[pix] = ((float)(c0 + li) + a) * (1.0f / 128.0f);
                }
            }
        }
    }
}

extern "C" void kernel_launch(void* const* d_in, const int* in_sizes, int n_in,
                              void* d_out, int out_size, void* d_ws, size_t ws_size,
                              hipStream_t stream)
{
    const float* x    = (const float*)d_in[0];
    const float* x_gt = (const float*)d_in[1];
    const float* Wc   = (const float*)d_in[2];
    const float* bc   = (const float*)d_in[3];
    const float* W1   = (const float*)d_in[4];
    const float* b1   = (const float*)d_in[5];
    const float* W2   = (const float*)d_in[6];
    const float* b2   = (const float*)d_in[7];
    const float* Wrc  = (const float*)d_in[8];
    const float* brc  = (const float*)d_in[9];
    float* out = (float*)d_out;

    const size_t lab_bytes = (size_t)HWP * sizeof(int);
    const size_t xT_bytes  = (size_t)HWP * 128 * sizeof(ushort);
    int use_xT = (ws_size >= lab_bytes + xT_bytes) ? 1 : 0;

    int*    labels = (int*)d_ws;
    ushort* xT     = (ushort*)((char*)d_ws + lab_bytes);

    hipLaunchKernelGGL(k1_mfma, dim3(5, HH), dim3(512), 0, stream,
                       x, x_gt, Wc, bc, out + 2 * (size_t)HWP, labels, xT, use_xT);
    if (use_xT)
        hipLaunchKernelGGL(k2_mfma<1>, dim3(CC / G, HH), dim3(256), 0, stream,
                           x, xT, labels, W1, b1, W2, b2, Wrc, brc, out);
    else
        hipLaunchKernelGGL(k2_mfma<0>, dim3(CC / G, HH), dim3(256), 0, stream,
                           x, xT, labels, W1, b1, W2, b2, Wrc, brc, out);
}

// Round 12
// 300.502 us; speedup vs baseline: 1.0710x; 1.0710x over previous
//
#include <hip/hip_runtime.h>
#include <hip/hip_bf16.h>

#define HH 448
#define WW 608
#define CC 128
#define HWP (HH*WW)
#define G 8   // experts per K2 block (4 waves x 2 rounds)

typedef __attribute__((ext_vector_type(8))) short bf16x8;
typedef __attribute__((ext_vector_type(4))) float f32x4;

__device__ __forceinline__ ushort f2b(float f) {
    __hip_bfloat16 b = __float2bfloat16(f);
    return *reinterpret_cast<ushort*>(&b);
}
__device__ __forceinline__ float b2f(ushort u) {
    union { unsigned v; float f; } x; x.v = ((unsigned)u) << 16; return x.f;
}
__device__ __forceinline__ float lrelu(float a) { return a > 0.f ? a : 0.01f * a; }

// Wcs swizzle: [m][k], k<128. group = (k>>3) ^ (m&15) -> frag reads 2-way (free)
__device__ __forceinline__ int swzA(int m, int k) {
    return m * 128 + ((((k >> 3) ^ (m & 15)) & 15) << 3) + (k & 7);
}
// Xs swizzle: [n][k], k<64. group = (k>>3) ^ (n&7) ^ ((n>>3)&7)
__device__ __forceinline__ int swzB(int n, int k) {
    return n * 64 + ((((k >> 3) ^ (n & 7) ^ ((n >> 3) & 7)) & 7) << 3) + (k & 7);
}

// ---------------- Kernel 1: MFMA classifier + in-register softmax/loss ----------------
__global__ __launch_bounds__(512, 4) void k1_mfma(
    const float* __restrict__ x, const float* __restrict__ x_gt,
    const float* __restrict__ Wc, const float* __restrict__ bc,
    float* __restrict__ loss_out, int* __restrict__ labels,
    ushort* __restrict__ xT, int use_xT)
{
    __shared__ ushort Wcs[128 * 128];
    __shared__ ushort Xs[128 * 64];
    __shared__ float bcs[128];

    const int h  = blockIdx.y;
    const int w0 = blockIdx.x * 128;
    const int t  = threadIdx.x;
    const int wv = t >> 6, l = t & 63;
    const int q  = l >> 4, lm = l & 15;
    const int nvalid = (WW - w0 < 128) ? (WW - w0) : 128;

    const float* Wch = Wc + (size_t)h * (CC * 128);
    #pragma unroll
    for (int it = 0; it < 8; ++it) {
        int f4 = t + (it << 9);
        float4 v = reinterpret_cast<const float4*>(Wch)[f4];
        int e = f4 << 2; int m = e >> 7, kk = e & 127;
        ushort4 u = make_ushort4(f2b(v.x), f2b(v.y), f2b(v.z), f2b(v.w));
        *reinterpret_cast<ushort4*>(&Wcs[swzA(m, kk)]) = u;
    }
    if (t < 128) bcs[t] = bc[h * CC + t];

    f32x4 acc[8];
    #pragma unroll
    for (int mt = 0; mt < 8; ++mt) acc[mt] = (f32x4){0.f, 0.f, 0.f, 0.f};

    for (int kh = 0; kh < 2; ++kh) {
        if (kh) __syncthreads();
        #pragma unroll
        for (int it = 0; it < 2; ++it) {
            int p = t + (it << 9);
            int i2 = p >> 5;
            int w = (p & 31) << 2;
            float4 v0, v1;
            if (w0 + w < WW) {
                const float* xb = x + ((size_t)(kh * 64 + i2 * 2)) * HWP + (size_t)h * WW + w0 + w;
                v0 = *reinterpret_cast<const float4*>(xb);
                v1 = *reinterpret_cast<const float4*>(xb + HWP);
            } else { v0 = make_float4(0, 0, 0, 0); v1 = v0; }
            int il = i2 << 1;
            *reinterpret_cast<ushort2*>(&Xs[swzB(w + 0, il)]) = make_ushort2(f2b(v0.x), f2b(v1.x));
            *reinterpret_cast<ushort2*>(&Xs[swzB(w + 1, il)]) = make_ushort2(f2b(v0.y), f2b(v1.y));
            *reinterpret_cast<ushort2*>(&Xs[swzB(w + 2, il)]) = make_ushort2(f2b(v0.z), f2b(v1.z));
            *reinterpret_cast<ushort2*>(&Xs[swzB(w + 3, il)]) = make_ushort2(f2b(v0.w), f2b(v1.w));
        }
        __syncthreads();

        #pragma unroll
        for (int kk = 0; kk < 2; ++kk) {
            const int kb = (kk << 5) + (q << 3);
            const int kg = (kh << 6) + kb;
            bf16x8 bfrag = *reinterpret_cast<const bf16x8*>(&Xs[swzB((wv << 4) + lm, kb)]);
            #pragma unroll
            for (int mt = 0; mt < 8; ++mt) {
                bf16x8 afrag = *reinterpret_cast<const bf16x8*>(&Wcs[swzA((mt << 4) + lm, kg)]);
                acc[mt] = __builtin_amdgcn_mfma_f32_16x16x32_bf16(afrag, bfrag, acc[mt], 0, 0, 0);
            }
        }

        if (use_xT) {
            #pragma unroll
            for (int it = 0; it < 2; ++it) {
                int g = t + (it << 9);
                int n = g >> 3, i8 = g & 7;
                if (n < nvalid) {
                    bf16x8 v = *reinterpret_cast<const bf16x8*>(&Xs[swzB(n, i8 << 3)]);
                    *reinterpret_cast<bf16x8*>(xT + ((size_t)(h * WW + w0 + n)) * 128 + (kh << 6) + (i8 << 3)) = v;
                }
            }
        }
    }

    const int cn = (wv << 4) + lm;
    const int w  = w0 + cn;
    float mx = -1e30f;
    #pragma unroll
    for (int mt = 0; mt < 8; ++mt)
        #pragma unroll
        for (int r = 0; r < 4; ++r) {
            float z = acc[mt][r] + bcs[(mt << 4) + (q << 2) + r];
            z = z > 0.f ? z : 0.01f * z;
            acc[mt][r] = z;
            mx = fmaxf(mx, z);
        }
    mx = fmaxf(mx, __shfl_xor(mx, 16));
    mx = fmaxf(mx, __shfl_xor(mx, 32));
    float s1 = 0.f;
    #pragma unroll
    for (int mt = 0; mt < 8; ++mt)
        #pragma unroll
        for (int r = 0; r < 4; ++r) {
            float ev = __expf(acc[mt][r] - mx);
            acc[mt][r] = ev;
            s1 += ev;
        }
    s1 += __shfl_xor(s1, 16);
    s1 += __shfl_xor(s1, 32);
    const float inv = 1.f / s1;
    float s2 = 0.f;
    #pragma unroll
    for (int mt = 0; mt < 8; ++mt)
        #pragma unroll
        for (int r = 0; r < 4; ++r) s2 += __expf(acc[mt][r] * inv);
    s2 += __shfl_xor(s2, 16);
    s2 += __shfl_xor(s2, 32);

    int lab = 0;
    if (w < WW) {
        float g = x_gt[(size_t)h * WW + w];
        lab = (int)(g * 128.f);
        lab = lab < 0 ? 0 : (lab > 127 ? 127 : lab);
    }
    float pl = 0.f;
    #pragma unroll
    for (int mt = 0; mt < 8; ++mt)
        #pragma unroll
        for (int r = 0; r < 4; ++r)
            if (((mt << 4) + (q << 2) + r) == lab) pl = acc[mt][r] * inv;
    pl += __shfl_xor(pl, 16);
    pl += __shfl_xor(pl, 32);

    if (q == 0 && w < WW) {
        loss_out[(size_t)h * WW + w] = __logf(s2) - pl;
        labels[h * WW + w] = lab;
    }
}

// ---------------- Kernel 2 (v4): MFMA expert MLP, one wave per expert ----------------
// grid (16, 448), block 256 (4 waves). Wave wv handles experts c0+wv and c0+wv+4.
// Weights go global->VGPR fragments directly (no broadcast-wasteful LDS reads).
// Per-wave private LDS only for the h/h2 layout transposes; no main-loop barriers.
__global__ __launch_bounds__(256, 2) void k2_mfma(
    const float* __restrict__ x, const ushort* __restrict__ xT, int use_xT,
    const int* __restrict__ labels,
    const float* __restrict__ W1, const float* __restrict__ b1,
    const float* __restrict__ W2, const float* __restrict__ b2,
    const float* __restrict__ Wrc, const float* __restrict__ brc,
    float* __restrict__ out)
{
    __shared__ ushort wlist[WW];
    __shared__ int cnt8[G], off8[G], cur8[G];
    __shared__ ushort __align__(16) hA[4][16][40];   // [wave][p][o] bf16, row 80B (16B-aligned)
    __shared__ float h2s[4][16][33];                 // [wave][p][o2] fp32
    __shared__ float wrcs[4][64];                    // [wave][o2*2+og]

    const int cg = blockIdx.x, h = blockIdx.y;
    const int c0 = cg * G;
    const size_t E0 = (size_t)h * CC + c0;
    const int t = threadIdx.x;
    const int wv = t >> 6, l = t & 63;
    const int lo = l & 15, g = l >> 4;   // frag col / k-octet group

    if (t < G) { cnt8[t] = 0; cur8[t] = 0; }
    __syncthreads();

    // ---- label scan + per-expert compaction (block-wide, once) ----
    const int* lrow = labels + h * WW;
    int myl[3];
    #pragma unroll
    for (int p = 0; p < 3; ++p) {
        int w = t + p * 256;
        myl[p] = (w < WW) ? (lrow[w] - c0) : -1;
        if (myl[p] >= 0 && myl[p] < G) atomicAdd(&cnt8[myl[p]], 1);
    }
    __syncthreads();
    if (t == 0) { int s = 0; for (int e2 = 0; e2 < G; ++e2) { off8[e2] = s; s += cnt8[e2]; } }
    __syncthreads();
    #pragma unroll
    for (int p = 0; p < 3; ++p) {
        int li = myl[p];
        if (li >= 0 && li < G) {
            int pos = off8[li] + atomicAdd(&cur8[li], 1);
            wlist[pos] = (ushort)(t + p * 256);
        }
    }
    __syncthreads();

    // ---- per-wave expert loop (no cross-wave sync below) ----
    for (int ei = 0; ei < 2; ++ei) {
        const int li = wv + ei * 4;
        const int e_n = cnt8[li], e_off = off8[li];
        if (e_n == 0) continue;
        const size_t eg = E0 + li;
        const float* W1e = W1 + eg * 4096;
        const float* W2e = W2 + eg * 1024;

        // -- load W1/W2 directly in B-fragment layout (all bytes of each line consumed
        //    across the two 16-col tiles), plus biases/Wrc --
        float w1f[4][2][8];   // [kstep][otile][j]  (static idx only)
        #pragma unroll
        for (int ks = 0; ks < 4; ++ks)
            #pragma unroll
            for (int tt = 0; tt < 2; ++tt)
                #pragma unroll
                for (int j = 0; j < 8; ++j)
                    w1f[ks][tt][j] = W1e[(ks * 32 + g * 8 + j) * 32 + tt * 16 + lo];
        float w2f[2][8];
        #pragma unroll
        for (int tt = 0; tt < 2; ++tt)
            #pragma unroll
            for (int j = 0; j < 8; ++j)
                w2f[tt][j] = W2e[(g * 8 + j) * 32 + tt * 16 + lo];
        const float b1v0 = b1[eg * 32 + lo],      b1v1 = b1[eg * 32 + 16 + lo];
        const float b2v0 = b2[eg * 32 + lo],      b2v1 = b2[eg * 32 + 16 + lo];
        const float brcv = brc[eg * 2 + (g & 1)];
        wrcs[wv][l] = Wrc[eg * 64 + l];

        bf16x8 w1b[4][2];
        #pragma unroll
        for (int ks = 0; ks < 4; ++ks)
            #pragma unroll
            for (int tt = 0; tt < 2; ++tt) {
                bf16x8 r;
                #pragma unroll
                for (int j = 0; j < 8; ++j) r[j] = (short)f2b(w1f[ks][tt][j]);
                w1b[ks][tt] = r;
            }
        bf16x8 w2b[2];
        #pragma unroll
        for (int tt = 0; tt < 2; ++tt) {
            bf16x8 r;
            #pragma unroll
            for (int j = 0; j < 8; ++j) r[j] = (short)f2b(w2f[tt][j]);
            w2b[tt] = r;
        }

        // -- pixel tiles of 16 --
        for (int pb = 0; pb < e_n; pb += 16) {
            int p_idx = pb + lo;
            int pc = (p_idx < e_n) ? p_idx : (e_n - 1);
            const int wpix = wlist[e_off + pc];

            // A1-frags: lane reads xT[pixel(lo)][k = ks*32 + g*8 .. +7] (bf16, contiguous)
            bf16x8 af[4];
            if (use_xT) {
                const ushort* xrow = xT + (((size_t)(h * WW + wpix)) << 7);
                #pragma unroll
                for (int ks = 0; ks < 4; ++ks)
                    af[ks] = *reinterpret_cast<const bf16x8*>(xrow + ks * 32 + g * 8);
            } else {
                #pragma unroll
                for (int ks = 0; ks < 4; ++ks) {
                    bf16x8 r;
                    #pragma unroll
                    for (int j = 0; j < 8; ++j) {
                        float f = x[(size_t)(ks * 32 + g * 8 + j) * HWP + (size_t)h * WW + wpix];
                        r[j] = (short)f2b(f);
                    }
                    af[ks] = r;
                }
            }

            // layer 1: D1[p][o] = X·W1 + b1
            f32x4 a1t0 = {b1v0, b1v0, b1v0, b1v0};
            f32x4 a1t1 = {b1v1, b1v1, b1v1, b1v1};
            #pragma unroll
            for (int ks = 0; ks < 4; ++ks) {
                a1t0 = __builtin_amdgcn_mfma_f32_16x16x32_bf16(af[ks], w1b[ks][0], a1t0, 0, 0, 0);
                a1t1 = __builtin_amdgcn_mfma_f32_16x16x32_bf16(af[ks], w1b[ks][1], a1t1, 0, 0, 0);
            }
            // lrelu -> hA[p][o] (row-major so layer-2 A-frag is one contiguous b128)
            #pragma unroll
            for (int r = 0; r < 4; ++r) {
                hA[wv][g * 4 + r][lo]      = f2b(lrelu(a1t0[r]));
                hA[wv][g * 4 + r][16 + lo] = f2b(lrelu(a1t1[r]));
            }
            // layer 2: A2 = h (lane: row=lo, k-octet=g*8), B2 = W2
            bf16x8 a2 = *reinterpret_cast<const bf16x8*>(&hA[wv][lo][g * 8]);
            f32x4 a2t0 = {b2v0, b2v0, b2v0, b2v0};
            f32x4 a2t1 = {b2v1, b2v1, b2v1, b2v1};
            a2t0 = __builtin_amdgcn_mfma_f32_16x16x32_bf16(a2, w2b[0], a2t0, 0, 0, 0);
            a2t1 = __builtin_amdgcn_mfma_f32_16x16x32_bf16(a2, w2b[1], a2t1, 0, 0, 0);
            #pragma unroll
            for (int r = 0; r < 4; ++r) {
                h2s[wv][g * 4 + r][lo]      = lrelu(a2t0[r]);
                h2s[wv][g * 4 + r][16 + lo] = lrelu(a2t1[r]);
            }
            // layer 3 (lanes 0..31): p = lo, og = g
            if (l < 32) {
                float a = brcv;
                #pragma unroll
                for (int i = 0; i < 32; ++i)
                    a = fmaf(h2s[wv][lo][i], wrcs[wv][i * 2 + g], a);
                a = lrelu(a);
                int p2 = pb + lo;
                if (p2 < e_n) {
                    int pix = h * WW + wlist[e_off + p2];
                    if (g == 1) out[HWP + pix] = a;
                    else        out[pix] = ((float)(c0 + li) + a) * (1.0f / 128.0f);
                }
            }
        }
    }
}

extern "C" void kernel_launch(void* const* d_in, const int* in_sizes, int n_in,
                              void* d_out, int out_size, void* d_ws, size_t ws_size,
                              hipStream_t stream)
{
    const float* x    = (const float*)d_in[0];
    const float* x_gt = (const float*)d_in[1];
    const float* Wc   = (const float*)d_in[2];
    const float* bc   = (const float*)d_in[3];
    const float* W1   = (const float*)d_in[4];
    const float* b1   = (const float*)d_in[5];
    const float* W2   = (const float*)d_in[6];
    const float* b2   = (const float*)d_in[7];
    const float* Wrc  = (const float*)d_in[8];
    const float* brc  = (const float*)d_in[9];
    float* out = (float*)d_out;

    const size_t lab_bytes = (size_t)HWP * sizeof(int);
    const size_t xT_bytes  = (size_t)HWP * 128 * sizeof(ushort);
    int use_xT = (ws_size >= lab_bytes + xT_bytes) ? 1 : 0;

    int*    labels = (int*)d_ws;
    ushort* xT     = (ushort*)((char*)d_ws + lab_bytes);

    hipLaunchKernelGGL(k1_mfma, dim3(5, HH), dim3(512), 0, stream,
                       x, x_gt, Wc, bc, out + 2 * (size_t)HWP, labels, xT, use_xT);
    hipLaunchKernelGGL(k2_mfma, dim3(CC / G, HH), dim3(256), 0, stream,
                       x, xT, use_xT, labels,
                       W1, b1, W2, b2, Wrc, brc, out);
}